// Round 5
// baseline (1169.237 us; speedup 1.0000x reference)
//
#include <hip/hip_runtime.h>
#include <hip/hip_bf16.h>
#include <math.h>

namespace {

constexpr int C_DIM  = 128;
constexpr int B_SZ   = 256;
constexpr int NP_OFF = 32768;         // np-graph node-id offset
constexpr int N_TOT  = 32896;         // 32768 + 128 combined rows
constexpr int E_P    = 524288;
constexpr int E_NP   = 2048;
constexpr int E_TOT  = E_P + E_NP;
constexpr int WALK   = 7;
constexpr int NTR    = 257;           // 256 p-block traces + 1 np trace
constexpr int NWIN   = 2;             // source windows (L2-resident gather)
constexpr int WIN_SHIFT = 14;         // window 0: src < 16384

typedef short bf16x8 __attribute__((ext_vector_type(8)));
typedef float f32x4 __attribute__((ext_vector_type(4)));

__device__ __forceinline__ float bfu(unsigned short u) {
  return __uint_as_float(((unsigned int)u) << 16);
}
__device__ __forceinline__ int win_of(int src) {
  int w = src >> WIN_SHIFT;           // 0,1 for p; 2 for np rows
  return w > 1 ? 1 : w;
}

// ---------------- precompute ----------------

__global__ void init_kernel(int* __restrict__ cnt2, float* __restrict__ tr) {
  int i = blockIdx.x * blockDim.x + threadIdx.x;
  if (i < NWIN * N_TOT) cnt2[i] = 0;
  if (i < WALK * NTR) tr[i] = 0.0f;
}

// harness delivers integer inputs as int32
__global__ void count_kernel(const int* __restrict__ ei_p,
                             const int* __restrict__ ei_np,
                             int* __restrict__ cnt2) {
  int e = blockIdx.x * blockDim.x + threadIdx.x;
  if (e < E_P) {
    int s = ei_p[e];
    int d = ei_p[E_P + e];
    atomicAdd(&cnt2[2 * d + win_of(s)], 1);
  } else if (e < E_TOT) {
    int i = e - E_P;
    int s = ei_np[i] + NP_OFF;
    int d = ei_np[E_NP + i] + NP_OFF;
    atomicAdd(&cnt2[2 * d + win_of(s)], 1);
  }
}

__global__ void dinv_kernel(const int* __restrict__ cnt2, float* __restrict__ dinv,
                            int* __restrict__ fill2) {
  int i = blockIdx.x * blockDim.x + threadIdx.x;
  if (i < N_TOT) {
    int deg = cnt2[2 * i] + cnt2[2 * i + 1];
    dinv[i] = rsqrtf((float)deg + 1.0f);  // +1 self loop
    fill2[2 * i] = 0;
    fill2[2 * i + 1] = 0;
  }
}

// single-block hierarchical exclusive scan of cnt2 -> ptr2 (length 2*N_TOT+1)
__global__ void scan_kernel(const int* __restrict__ cnt2, int* __restrict__ ptr2) {
  const int T = 1024;
  const int M = NWIN * N_TOT;
  __shared__ int part[T];
  int tid = threadIdx.x;
  const int chunk = (M + T - 1) / T;
  int begin = tid * chunk;
  int end = begin + chunk;
  if (end > M) end = M;
  if (begin > M) begin = M;
  int s = 0;
  for (int i = begin; i < end; ++i) s += cnt2[i];
  part[tid] = s;
  __syncthreads();
  for (int off = 1; off < T; off <<= 1) {
    int v = (tid >= off) ? part[tid - off] : 0;
    __syncthreads();
    part[tid] += v;
    __syncthreads();
  }
  if (tid == T - 1) ptr2[M] = part[T - 1];
  int run = (tid == 0) ? 0 : part[tid - 1];
  for (int i = begin; i < end; ++i) { ptr2[i] = run; run += cnt2[i]; }
}

__global__ void fill_kernel(const int* __restrict__ ei_p,
                            const int* __restrict__ ei_np,
                            const int* __restrict__ ptr2, int* __restrict__ fill2,
                            const float* __restrict__ dinv,
                            int* __restrict__ csr_src, float* __restrict__ csr_norm) {
  int e = blockIdx.x * blockDim.x + threadIdx.x;
  int s, d;
  if (e < E_P) {
    s = ei_p[e];
    d = ei_p[E_P + e];
  } else if (e < E_TOT) {
    int i = e - E_P;
    s = ei_np[i] + NP_OFF;
    d = ei_np[E_NP + i] + NP_OFF;
  } else {
    return;
  }
  int slot = 2 * d + win_of(s);
  int pos = ptr2[slot] + atomicAdd(&fill2[slot], 1);
  csr_src[pos] = s;
  csr_norm[pos] = dinv[s] * dinv[d];
}

// h0 = round_bf16([x_p ; x_np])
__global__ void concat_kernel(const float* __restrict__ x_p,
                              const float* __restrict__ x_np,
                              __hip_bfloat16* __restrict__ hb) {
  int i = blockIdx.x * blockDim.x + threadIdx.x;  // 8-elem chunk index
  const int NP8 = NP_OFF * C_DIM / 8;
  const int NT8 = N_TOT * C_DIM / 8;
  if (i >= NT8) return;
  const float* src = (i < NP8) ? (x_p + (size_t)i * 8)
                               : (x_np + (size_t)(i - NP8) * 8);
  union { __hip_bfloat16 h[8]; uint4 u; } pk;
#pragma unroll
  for (int j = 0; j < 8; ++j) pk.h[j] = __float2bfloat16(src[j]);
  ((uint4*)hb)[i] = pk.u;
}

// Wt[n][k] = bf16(W[k][n])
__global__ void wtrans_kernel(const float* __restrict__ W,
                              __hip_bfloat16* __restrict__ Wt) {
  int i = blockIdx.x * blockDim.x + threadIdx.x;
  if (i >= C_DIM * C_DIM) return;
  int n = i & 127, k = i >> 7;
  Wt[n * C_DIM + k] = __float2bfloat16(W[i]);
}

// ---------------- per-step kernels ----------------

// xw = h @ W via MFMA bf16. Wt staged in LDS (pitch 132 halves -> 2-way-free
// banks for ds_read_b128). Block = 4 waves x 16 rows = 64 rows.
constexpr int BP = 132;  // LDS row pitch in halves

__global__ __launch_bounds__(256) void gemm_kernel(const __hip_bfloat16* __restrict__ hb,
                                                   const __hip_bfloat16* __restrict__ Wt,
                                                   __hip_bfloat16* __restrict__ xwb) {
  __shared__ __hip_bfloat16 Bs[C_DIM * BP];
  {
    // stage Wt: thread t copies row r=t>>1, halves [(t&1)*64, +64)
    const int t = threadIdx.x;
    const int r = t >> 1;
    const int off = (t & 1) * 64;
    const uint4* src = (const uint4*)(Wt + (size_t)r * C_DIM + off);
    uint4* dst = (uint4*)(&Bs[r * BP + off]);
#pragma unroll
    for (int i = 0; i < 8; ++i) dst[i] = src[i];
  }
  __syncthreads();

  const int wave = threadIdx.x >> 6;
  const int lane = threadIdx.x & 63;
  const int q = lane >> 4;
  const int l16 = lane & 15;
  const int m_base = blockIdx.x * 64 + wave * 16;
  const int m = m_base + l16;

  bf16x8 a[4];
#pragma unroll
  for (int kc = 0; kc < 4; ++kc)
    a[kc] = *(const bf16x8*)(hb + (size_t)m * C_DIM + kc * 32 + q * 8);

#pragma unroll
  for (int j = 0; j < 8; ++j) {
    const int n = j * 16 + l16;
    f32x4 acc = {0.f, 0.f, 0.f, 0.f};
#pragma unroll
    for (int kc = 0; kc < 4; ++kc) {
      bf16x8 b = *(const bf16x8*)(&Bs[n * BP + kc * 32 + q * 8]);
      acc = __builtin_amdgcn_mfma_f32_16x16x32_bf16(a[kc], b, acc, 0, 0, 0);
    }
#pragma unroll
    for (int r = 0; r < 4; ++r)
      xwb[(size_t)(m_base + q * 4 + r) * C_DIM + n] = __float2bfloat16(acc[r]);
  }
}

// Aggregation phase 0: edges with src in window 0 only -> hacc (fp32 partial).
// One wave per node; 4 parallel edge chains; 16B bf16 gathers.
__global__ __launch_bounds__(256) void agg_phase0(const __hip_bfloat16* __restrict__ xwb,
                                                  float* __restrict__ hacc,
                                                  const int* __restrict__ ptr2,
                                                  const int* __restrict__ srcs,
                                                  const float* __restrict__ norms) {
  const int wave = threadIdx.x >> 6;
  const int lane = threadIdx.x & 63;
  const int q   = lane >> 4;
  const int c8  = lane & 15;
  const int node = blockIdx.x * 4 + wave;

  const int e0 = ptr2[2 * node];
  const int e1 = ptr2[2 * node + 1];
  const uint4* __restrict__ xw16 = (const uint4*)xwb;

  float acc[8];
#pragma unroll
  for (int i = 0; i < 8; ++i) acc[i] = 0.f;

  int e = e0 + q;
  for (; e + 4 < e1; e += 8) {
    int   s0 = srcs[e],  s1 = srcs[e + 4];
    float n0 = norms[e], n1 = norms[e + 4];
    uint4 r0 = xw16[(size_t)s0 * 16 + c8];
    uint4 r1 = xw16[(size_t)s1 * 16 + c8];
    unsigned int w0[4] = {r0.x, r0.y, r0.z, r0.w};
    unsigned int w1[4] = {r1.x, r1.y, r1.z, r1.w};
#pragma unroll
    for (int i = 0; i < 4; ++i) {
      acc[2 * i]     += n0 * __uint_as_float(w0[i] << 16)
                      + n1 * __uint_as_float(w1[i] << 16);
      acc[2 * i + 1] += n0 * __uint_as_float(w0[i] & 0xffff0000u)
                      + n1 * __uint_as_float(w1[i] & 0xffff0000u);
    }
  }
  for (; e < e1; e += 4) {
    int   s = srcs[e];
    float nv = norms[e];
    uint4 r = xw16[(size_t)s * 16 + c8];
    unsigned int w[4] = {r.x, r.y, r.z, r.w};
#pragma unroll
    for (int i = 0; i < 4; ++i) {
      acc[2 * i]     += nv * __uint_as_float(w[i] << 16);
      acc[2 * i + 1] += nv * __uint_as_float(w[i] & 0xffff0000u);
    }
  }

#pragma unroll
  for (int i = 0; i < 8; ++i) {
    acc[i] += __shfl_xor(acc[i], 16);
    acc[i] += __shfl_xor(acc[i], 32);
  }

  if (q == 0) {
    float4 h0 = make_float4(acc[0], acc[1], acc[2], acc[3]);
    float4 h1 = make_float4(acc[4], acc[5], acc[6], acc[7]);
    ((float4*)hacc)[(size_t)node * 32 + c8 * 2]     = h0;
    ((float4*)hacc)[(size_t)node * 32 + c8 * 2 + 1] = h1;
  }
}

// Aggregation phase 1: window-1 edges + hacc + self + bias -> hb (bf16) + trace
__global__ __launch_bounds__(256) void agg_phase1(const __hip_bfloat16* __restrict__ xwb,
                                                  const float* __restrict__ hacc,
                                                  __hip_bfloat16* __restrict__ hb,
                                                  const int* __restrict__ ptr2,
                                                  const int* __restrict__ srcs,
                                                  const float* __restrict__ norms,
                                                  const float* __restrict__ dinv,
                                                  const float* __restrict__ bias,
                                                  float* __restrict__ tr, int step) {
  const int wave = threadIdx.x >> 6;
  const int lane = threadIdx.x & 63;
  const int q   = lane >> 4;
  const int c8  = lane & 15;
  const int node = blockIdx.x * 4 + wave;

  const int e0 = ptr2[2 * node + 1];
  const int e1 = ptr2[2 * node + 2];
  const uint4* __restrict__ xw16 = (const uint4*)xwb;

  float acc[8];
#pragma unroll
  for (int i = 0; i < 8; ++i) acc[i] = 0.f;

  int e = e0 + q;
  for (; e + 4 < e1; e += 8) {
    int   s0 = srcs[e],  s1 = srcs[e + 4];
    float n0 = norms[e], n1 = norms[e + 4];
    uint4 r0 = xw16[(size_t)s0 * 16 + c8];
    uint4 r1 = xw16[(size_t)s1 * 16 + c8];
    unsigned int w0[4] = {r0.x, r0.y, r0.z, r0.w};
    unsigned int w1[4] = {r1.x, r1.y, r1.z, r1.w};
#pragma unroll
    for (int i = 0; i < 4; ++i) {
      acc[2 * i]     += n0 * __uint_as_float(w0[i] << 16)
                      + n1 * __uint_as_float(w1[i] << 16);
      acc[2 * i + 1] += n0 * __uint_as_float(w0[i] & 0xffff0000u)
                      + n1 * __uint_as_float(w1[i] & 0xffff0000u);
    }
  }
  for (; e < e1; e += 4) {
    int   s = srcs[e];
    float nv = norms[e];
    uint4 r = xw16[(size_t)s * 16 + c8];
    unsigned int w[4] = {r.x, r.y, r.z, r.w};
#pragma unroll
    for (int i = 0; i < 4; ++i) {
      acc[2 * i]     += nv * __uint_as_float(w[i] << 16);
      acc[2 * i + 1] += nv * __uint_as_float(w[i] & 0xffff0000u);
    }
  }

#pragma unroll
  for (int i = 0; i < 8; ++i) {
    acc[i] += __shfl_xor(acc[i], 16);
    acc[i] += __shfl_xor(acc[i], 32);
  }

  if (q == 0) {
    const float di = dinv[node];
    const float dd = di * di;
    uint4 sr = xw16[(size_t)node * 16 + c8];
    unsigned int sw[4] = {sr.x, sr.y, sr.z, sr.w};
    float4 p0 = ((const float4*)hacc)[(size_t)node * 32 + c8 * 2];
    float4 p1 = ((const float4*)hacc)[(size_t)node * 32 + c8 * 2 + 1];
    float pp[8] = {p0.x, p0.y, p0.z, p0.w, p1.x, p1.y, p1.z, p1.w};
    float4 b0 = ((const float4*)bias)[c8 * 2];
    float4 b1 = ((const float4*)bias)[c8 * 2 + 1];
    float bb[8] = {b0.x, b0.y, b0.z, b0.w, b1.x, b1.y, b1.z, b1.w};
    float outv[8];
#pragma unroll
    for (int i = 0; i < 4; ++i) {
      outv[2 * i]     = bb[2 * i]     + pp[2 * i]     + dd * __uint_as_float(sw[i] << 16)         + acc[2 * i];
      outv[2 * i + 1] = bb[2 * i + 1] + pp[2 * i + 1] + dd * __uint_as_float(sw[i] & 0xffff0000u) + acc[2 * i + 1];
    }
    union { __hip_bfloat16 h[8]; uint4 u; } pk;
#pragma unroll
    for (int i = 0; i < 8; ++i) pk.h[i] = __float2bfloat16(outv[i]);
    ((uint4*)hb)[(size_t)node * 16 + c8] = pk.u;

    const int dcol = node & 127;
    if (c8 == (dcol >> 3)) {
      atomicAdd(&tr[step * NTR + (node >> 7)], outv[dcol & 7]);
    }
  }
}

// Last walk step: only diagonal entries needed. 16 lanes per node, one edge
// per lane (2-B gathers), quarter shfl reduction.
__global__ __launch_bounds__(256) void trace_kernel(const __hip_bfloat16* __restrict__ xwb,
                                                    const int* __restrict__ ptr2,
                                                    const int* __restrict__ srcs,
                                                    const float* __restrict__ norms,
                                                    const float* __restrict__ dinv,
                                                    const float* __restrict__ bias,
                                                    float* __restrict__ tr, int step) {
  const int node = blockIdx.x * 16 + (threadIdx.x >> 4);
  const int sub = threadIdx.x & 15;
  const unsigned short* xu = (const unsigned short*)xwb;
  const int dcol = node & 127;
  const int e0 = ptr2[2 * node];
  const int e1 = ptr2[2 * node + 2];
  float acc = 0.f;
  for (int e = e0 + sub; e < e1; e += 16)
    acc += norms[e] * bfu(xu[(size_t)srcs[e] * C_DIM + dcol]);
  acc += __shfl_xor(acc, 1);
  acc += __shfl_xor(acc, 2);
  acc += __shfl_xor(acc, 4);
  acc += __shfl_xor(acc, 8);
  if (sub == 0) {
    const float di = dinv[node];
    acc += bias[dcol] + di * di * bfu(xu[(size_t)node * C_DIM + dcol]);
    atomicAdd(&tr[step * NTR + (node >> 7)], acc);
  }
}

// ---------------- epilogue ----------------

__global__ __launch_bounds__(256) void final_kernel(const float* __restrict__ tr,
                                                    const float* __restrict__ y,
                                                    const float* __restrict__ W1,
                                                    const float* __restrict__ b1,
                                                    const float* __restrict__ W2,
                                                    const float* __restrict__ b2,
                                                    float* __restrict__ out) {
  __shared__ float sm[B_SZ];
  const int b = threadIdx.x;
  const float sgn = (y[b] - 0.5f) * 2.0f;
  float vals[WALK];
#pragma unroll
  for (int t = 0; t < WALK; ++t)
    vals[t] = (tr[t * NTR + b] - tr[t * NTR + 256]) * sgn;

  for (int t = 0; t < WALK; ++t) {
    sm[b] = vals[t];
    __syncthreads();
    for (int off = 128; off >= 1; off >>= 1) {
      if (b < off) sm[b] += sm[b + off];
      __syncthreads();
    }
    float mean = sm[0] * (1.0f / 256.0f);
    __syncthreads();
    float d = vals[t] - mean;
    sm[b] = d * d;
    __syncthreads();
    for (int off = 128; off >= 1; off >>= 1) {
      if (b < off) sm[b] += sm[b + off];
      __syncthreads();
    }
    float stdv = sqrtf(sm[0] * (1.0f / 255.0f));  // ddof=1
    __syncthreads();
    vals[t] = d / stdv;
  }

  float o = b2[0];
#pragma unroll
  for (int j = 0; j < 15; ++j) {
    float a = b1[j];
#pragma unroll
    for (int t = 0; t < WALK; ++t) a += vals[t] * W1[t * 15 + j];
    o += fmaxf(a, 0.0f) * W2[j];
  }
  out[b] = 1.0f / (1.0f + expf(-o));
}

}  // namespace

extern "C" void kernel_launch(void* const* d_in, const int* in_sizes, int n_in,
                              void* d_out, int out_size, void* d_ws, size_t ws_size,
                              hipStream_t stream) {
  const float* x_p   = (const float*)d_in[0];
  const float* x_np  = (const float*)d_in[1];
  const float* y     = (const float*)d_in[2];
  const int* ei_p    = (const int*)d_in[3];   // int inputs arrive as int32
  const int* ei_np   = (const int*)d_in[4];
  const float* W_gcn = (const float*)d_in[5];
  const float* b_gcn = (const float*)d_in[6];
  const float* W1    = (const float*)d_in[7];
  const float* b1    = (const float*)d_in[8];
  const float* W2    = (const float*)d_in[9];
  const float* b2    = (const float*)d_in[10];
  float* out         = (float*)d_out;

  char* p = (char*)d_ws;
  auto alloc = [&](size_t bytes) -> void* {
    void* r = (void*)p;
    p += (bytes + 255) & ~(size_t)255;
    return r;
  };
  __hip_bfloat16* hb  = (__hip_bfloat16*)alloc((size_t)N_TOT * C_DIM * 2);
  __hip_bfloat16* xwb = (__hip_bfloat16*)alloc((size_t)N_TOT * C_DIM * 2);
  float* hacc     = (float*)alloc((size_t)N_TOT * C_DIM * 4);  // fp32 partials
  __hip_bfloat16* Wt  = (__hip_bfloat16*)alloc((size_t)C_DIM * C_DIM * 2);
  float* dinv     = (float*)alloc((size_t)N_TOT * 4);
  int*   cnt2     = (int*)alloc((size_t)NWIN * N_TOT * 4);
  int*   fill2    = (int*)alloc((size_t)NWIN * N_TOT * 4);
  int*   ptr2     = (int*)alloc((size_t)(NWIN * N_TOT + 1) * 4);
  int*   csr_src  = (int*)alloc((size_t)E_TOT * 4);
  float* csr_norm = (float*)alloc((size_t)E_TOT * 4);
  float* tr       = (float*)alloc((size_t)WALK * NTR * 4);

  // --- precompute ---
  init_kernel<<<(NWIN * N_TOT + 255) / 256, 256, 0, stream>>>(cnt2, tr);
  count_kernel<<<(E_TOT + 255) / 256, 256, 0, stream>>>(ei_p, ei_np, cnt2);
  dinv_kernel<<<(N_TOT + 255) / 256, 256, 0, stream>>>(cnt2, dinv, fill2);
  scan_kernel<<<1, 1024, 0, stream>>>(cnt2, ptr2);
  fill_kernel<<<(E_TOT + 255) / 256, 256, 0, stream>>>(ei_p, ei_np, ptr2, fill2,
                                                       dinv, csr_src, csr_norm);
  wtrans_kernel<<<(C_DIM * C_DIM + 255) / 256, 256, 0, stream>>>(W_gcn, Wt);
  {
    const int NT8 = N_TOT * C_DIM / 8;
    concat_kernel<<<(NT8 + 255) / 256, 256, 0, stream>>>(x_p, x_np, hb);
  }

  // --- 7 walk steps ---
  for (int t = 0; t < WALK; ++t) {
    gemm_kernel<<<N_TOT / 64, 256, 0, stream>>>(hb, Wt, xwb);
    if (t < WALK - 1) {
      agg_phase0<<<N_TOT / 4, 256, 0, stream>>>(xwb, hacc, ptr2, csr_src, csr_norm);
      agg_phase1<<<N_TOT / 4, 256, 0, stream>>>(xwb, hacc, hb, ptr2, csr_src,
                                                csr_norm, dinv, b_gcn, tr, t);
    } else {
      trace_kernel<<<N_TOT / 16, 256, 0, stream>>>(xwb, ptr2, csr_src, csr_norm,
                                                   dinv, b_gcn, tr, t);
    }
  }

  // --- standardize + MLP + sigmoid ---
  final_kernel<<<1, B_SZ, 0, stream>>>(tr, y, W1, b1, W2, b2, out);
}